// Round 3
// baseline (149.623 us; speedup 1.0000x reference)
//
#include <hip/hip_runtime.h>

#define BN 4096
#define KD 256
#define TILE 256
#define BK 64

typedef short bf16x8 __attribute__((ext_vector_type(8)));
typedef float f32x4 __attribute__((ext_vector_type(4)));
typedef unsigned short ushort_t;
typedef unsigned int uint_t;

// 256x256 tile slots: z=0 upper-tri 136, z=1 upper-tri 136, z=2 full 256 -> 528
#define NSLOT 528

__device__ inline void async_load16(const void* g, void* l) {
    __builtin_amdgcn_global_load_lds((const __attribute__((address_space(1))) void*)g,
                                     (__attribute__((address_space(3))) void*)l,
                                     16, 0, 0);
}

__device__ inline ushort_t f2bf(float f) {
    union { float f; unsigned int u; } x;
    x.f = f;
    unsigned int u = x.u;
    unsigned int r = (u + 0x7fffu + ((u >> 16) & 1u)) >> 16;  // RTNE
    return (ushort_t)r;
}

__device__ __forceinline__ float fast_sqrt(float x) {
    return __builtin_amdgcn_sqrtf(x);     // v_sqrt_f32
}
__device__ __forceinline__ float fast_exp2(float x) {
    return __builtin_amdgcn_exp2f(x);     // v_exp_f32
}

__device__ __forceinline__ void decode_slot(int slot, int& z, int& bi, int& bj) {
    if (slot >= 272) {
        z = 2; int t = slot - 272; bi = t >> 4; bj = t & 15;
    } else {
        z = (slot >= 136) ? 1 : 0;
        int t = slot - z * 136;
        // triangular n=16: row b starts at cum(b) = b*(33-b)/2
        int b = (int)(16.5f - sqrtf(272.25f - 2.0f * (float)t));
        while (b * (33 - b) / 2 > t) --b;
        while ((b + 1) * (32 - b) / 2 <= t) ++b;
        bi = b;
        bj = bi + (t - bi * (33 - bi) / 2);
    }
}

// Kernel 0: fp32 row norms + bf16 (RTNE) copies of xs, xt.
__global__ __launch_bounds__(256) void norm_cvt(
        const float* __restrict__ xs, const float* __restrict__ xt,
        ushort_t* __restrict__ xsb, ushort_t* __restrict__ xtb,
        float* __restrict__ norms) {
    int w = threadIdx.x >> 6;
    int lane = threadIdx.x & 63;
    int row = blockIdx.x * 4 + w;              // 0..8191
    const float* src = (row < BN) ? xs + (size_t)row * KD
                                  : xt + (size_t)(row - BN) * KD;
    ushort_t* dst = (row < BN) ? xsb + (size_t)row * KD
                               : xtb + (size_t)(row - BN) * KD;
    float4 v = ((const float4*)src)[lane];
    float s = v.x * v.x + v.y * v.y + v.z * v.z + v.w * v.w;
#pragma unroll
    for (int off = 32; off > 0; off >>= 1) s += __shfl_xor(s, off, 64);
    if (lane == 0) norms[row] = s;
    ushort4 o;
    o.x = f2bf(v.x); o.y = f2bf(v.y); o.z = f2bf(v.z); o.w = f2bf(v.w);
    ((ushort4*)dst)[lane] = o;
}

// -------- distance GEMM (256^2 tile, 8 waves, dbuf'd LDS, counted vmcnt), run twice --------
// PASS 1: per-tile sum of d -> p1[slot] (plain store, c1-weighted)
// PASS 2: self-reduce p1 -> per-z mean, recompute d, exp-sum -> p2[slot]

template <int PASS>
__global__ __launch_bounds__(512, 2) void mmd_gemm(
        const ushort_t* __restrict__ xsb, const ushort_t* __restrict__ xtb,
        const float* __restrict__ norms,
        const float* __restrict__ p1, float* __restrict__ pout) {
    const int slot = blockIdx.x;
    int z, bi, bj;
    decode_slot(slot, z, bi, bj);

    const ushort_t* X = (z == 1) ? xtb : xsb;
    const ushort_t* Y = (z == 0) ? xsb : xtb;
    const float* nX = norms + ((z == 1) ? BN : 0);
    const float* nY = norms + ((z == 0) ? 0 : BN);

    const int tid = threadIdx.x;
    const int lane = tid & 63;
    const int w = tid >> 6;          // 0..7
    const int wr = w >> 2;           // 0..1 : 128-row band
    const int wc = w & 3;            // 0..3 : 64-col band
    const int m16 = lane & 15;
    const int q = lane >> 4;         // 0..3

    const int i0 = bi * TILE;
    const int j0 = bj * TILE;

    // LDS: double-buffered A,B tiles: 2 bufs x 2 (A,B) x 256x64 bf16 = 128 KiB
    __shared__ ushort_t sm[2][2][TILE * BK];
    __shared__ float red[8];
    __shared__ double rs[8][3];

    // PASS 2: self-reduce the 528 pass-1 tile partials (L2-hot ~2 KB) into per-z sums.
    float nhb = 0.0f;
    if (PASS == 2) {
        double a0 = 0.0, a1 = 0.0, a2 = 0.0;
        for (int s = tid; s < NSLOT; s += 512) {
            double v = (double)p1[s];
            if (s < 136) a0 += v; else if (s < 272) a1 += v; else a2 += v;
        }
#pragma unroll
        for (int off = 32; off > 0; off >>= 1) {
            a0 += __shfl_xor(a0, off, 64);
            a1 += __shfl_xor(a1, off, 64);
            a2 += __shfl_xor(a2, off, 64);
        }
        if (lane == 0) { rs[w][0] = a0; rs[w][1] = a1; rs[w][2] = a2; }
        __syncthreads();
        double sz = 0.0;
#pragma unroll
        for (int ww = 0; ww < 8; ++ww) sz += rs[ww][z];
        double mz = sz * (1.0 / 16777216.0);              // mean over 4096^2
        nhb = (float)(-1.4426950408889634 / (4.0 * mz));  // alpha=2 exponent scale
    }

    // staging geometry: per k-step, A tile = 2048 x 16B chunks, B same.
    // thread -> (row, chunk): chunk_id = t*512 + tid; r = t*64 + (tid>>3); c = tid&7.
    // XOR-swizzled source column, linear LDS dest (global_load_lds constraint).
    const int rbase = tid >> 3;
    const int gc = (tid & 7) ^ (rbase & 7);     // t-invariant: (t*64)%8 == 0
    const size_t baseA = (size_t)(i0 + rbase) * KD + gc * 8;
    const size_t baseB = (size_t)(j0 + rbase) * KD + gc * 8;

    f32x4 acc[8][4] = {};

    auto stage = [&](int kt, int p) {
        const int kk = kt * BK;
        char* ldsA = (char*)&sm[p][0][0];
        char* ldsB = (char*)&sm[p][1][0];
#pragma unroll
        for (int t = 0; t < 4; ++t) {
            async_load16(X + baseA + (size_t)t * 64 * KD + kk, ldsA + t * 8192 + tid * 16);
            async_load16(Y + baseB + (size_t)t * 64 * KD + kk, ldsB + t * 8192 + tid * 16);
        }
    };

    auto compute = [&](int p) {
#pragma unroll
        for (int ks = 0; ks < 2; ++ks) {
            bf16x8 af[8], bfv[4];
            const int kap = ks * 4 + q;
            const int pos = kap ^ (m16 & 7);    // row&7 == m16&7 for all fragment rows
#pragma unroll
            for (int rg = 0; rg < 8; ++rg)
                af[rg] = *(const bf16x8*)&sm[p][0][(wr * 128 + rg * 16 + m16) * BK + pos * 8];
#pragma unroll
            for (int ng = 0; ng < 4; ++ng)
                bfv[ng] = *(const bf16x8*)&sm[p][1][(wc * 64 + ng * 16 + m16) * BK + pos * 8];
#pragma unroll
            for (int rg = 0; rg < 8; ++rg)
#pragma unroll
                for (int ng = 0; ng < 4; ++ng)
                    acc[rg][ng] = __builtin_amdgcn_mfma_f32_16x16x32_bf16(
                        af[rg], bfv[ng], acc[rg][ng], 0, 0, 0);
        }
    };

    // K-loop: 4 steps, double-buffered, counted vmcnt (never drain prefetch).
    stage(0, 0);
#pragma unroll
    for (int t = 0; t < 4; ++t) {
        const int p = t & 1;
        if (t < 3) {
            stage(t + 1, p ^ 1);
            asm volatile("s_waitcnt vmcnt(8)" ::: "memory");   // buf p's 8 loads done
        } else {
            asm volatile("s_waitcnt vmcnt(0)" ::: "memory");
        }
        __builtin_amdgcn_s_barrier();
        compute(p);
        if (t < 3) __builtin_amdgcn_s_barrier();   // readers of buf p done before t+1 restages it
    }

    // norms: loaded after the K-loop so they never perturb vmcnt counting.
    float nxv[32];
#pragma unroll
    for (int rg = 0; rg < 8; ++rg) {
        float4 nf = *(const float4*)&nX[i0 + wr * 128 + rg * 16 + q * 4];
        nxv[rg * 4 + 0] = nf.x; nxv[rg * 4 + 1] = nf.y;
        nxv[rg * 4 + 2] = nf.z; nxv[rg * 4 + 3] = nf.w;
    }
    float nyv[4];
#pragma unroll
    for (int ng = 0; ng < 4; ++ng)
        nyv[ng] = nY[j0 + wc * 64 + ng * 16 + m16];

    const bool diag = (z < 2 && bi == bj);
    float local = 0.0f;
#pragma unroll
    for (int rg = 0; rg < 8; ++rg) {
#pragma unroll
        for (int ng = 0; ng < 4; ++ng) {
#pragma unroll
            for (int rr = 0; rr < 4; ++rr) {
                int i = wr * 128 + rg * 16 + q * 4 + rr;   // tile-local
                int j = wc * 64 + ng * 16 + m16;
                float sq = nxv[rg * 4 + rr] + nyv[ng] - 2.0f * acc[rg][ng][rr];
                sq = fmaxf(sq, 0.0f);
                float d = fast_sqrt(sq);
                if (diag && i == j) d = 0.0f;              // exact-zero diagonal
                if (PASS == 1) {
                    local += d;
                } else {
                    // sum over alphas {1/8,1/4,1/2,1,2}: u+u^2+u^4+u^8+u^16, u=2^(d*nhb)
                    float u = fast_exp2(d * nhb);
                    float u2 = u * u;
                    float u4 = u2 * u2;
                    float u8 = u4 * u4;
                    float u16 = u8 * u8;
                    local += (u + u2) + (u4 + u8) + u16;
                }
            }
        }
    }

#pragma unroll
    for (int off = 32; off > 0; off >>= 1) local += __shfl_xor(local, off, 64);
    if (lane == 0) red[w] = local;
    __syncthreads();
    if (tid == 0) {
        float bs = 0.0f;
#pragma unroll
        for (int ww = 0; ww < 8; ++ww) bs += red[ww];
        float coef;
        if (PASS == 1) coef = (z < 2 && bi != bj) ? 2.0f : 1.0f;   // mean weight
        else           coef = (z == 2) ? -2.0f : ((bi != bj) ? 2.0f : 1.0f);
        pout[slot] = coef * bs;                        // plain store, no atomic
    }
}

// -------- finalize: reduce pass-2 tile partials -> loss (1 block) --------

__global__ __launch_bounds__(256) void mmd_finalize2(
        const float* __restrict__ p2, float* __restrict__ out) {
    const int tid = threadIdx.x;
    double acc = 0.0;
    for (int s = tid; s < NSLOT; s += 256) acc += (double)p2[s];
    const int lane = tid & 63, w = tid >> 6;
#pragma unroll
    for (int off = 32; off > 0; off >>= 1) acc += __shfl_xor(acc, off, 64);
    __shared__ double r[4];
    if (lane == 0) r[w] = acc;
    __syncthreads();
    if (tid == 0) {
        double S = r[0] + r[1] + r[2] + r[3];
        double l = sqrt(S / ((double)BN * (double)(BN - 1)));
        float f = (float)l;
        if (!(f == f)) f = 0.0f;
        out[0] = f;
    }
}

extern "C" void kernel_launch(void* const* d_in, const int* in_sizes, int n_in,
                              void* d_out, int out_size, void* d_ws, size_t ws_size,
                              hipStream_t stream) {
    const float* xs = (const float*)d_in[0];
    const float* xt = (const float*)d_in[1];
    float* out = (float*)d_out;

    char* ws = (char*)d_ws;
    float* norms = (float*)ws;                     // 8192 floats -> 32768
    float* p1 = (float*)(ws + 32768);              // 528 floats -> pad to 35072
    float* p2 = (float*)(ws + 35072);              // 528 floats -> pad to 37376
    ushort_t* xsb = (ushort_t*)(ws + 37376);       // 2 MB
    ushort_t* xtb = xsb + (size_t)BN * KD;         // 2 MB -> ends 4231680

    size_t need = 4231680;
    if (ws_size < need) {
        (void)hipMemsetAsync(d_out, 0xC0, 4, stream);    // diagnostic marker
        return;
    }

    norm_cvt<<<2048, 256, 0, stream>>>(xs, xt, xsb, xtb, norms);
    mmd_gemm<1><<<NSLOT, 512, 0, stream>>>(xsb, xtb, norms, p1, p1);
    mmd_gemm<2><<<NSLOT, 512, 0, stream>>>(xsb, xtb, norms, p1, p2);
    mmd_finalize2<<<1, 256, 0, stream>>>(p2, out);
}

// Round 4
// 148.708 us; speedup vs baseline: 1.0062x; 1.0062x over previous
//
#include <hip/hip_runtime.h>

#define BN 4096
#define KD 256
#define TILE 256
#define BK 64

typedef short bf16x8 __attribute__((ext_vector_type(8)));
typedef float f32x4 __attribute__((ext_vector_type(4)));
typedef unsigned short ushort_t;
typedef unsigned int uint_t;

// 256x256 tile slots: z=0 upper-tri 136, z=1 upper-tri 136, z=2 full 256 -> 528
#define NSLOT 528

__device__ inline void async_load16(const void* g, void* l) {
    __builtin_amdgcn_global_load_lds((const __attribute__((address_space(1))) void*)g,
                                     (__attribute__((address_space(3))) void*)l,
                                     16, 0, 0);
}

__device__ inline ushort_t f2bf(float f) {
    union { float f; unsigned int u; } x;
    x.f = f;
    unsigned int u = x.u;
    unsigned int r = (u + 0x7fffu + ((u >> 16) & 1u)) >> 16;  // RTNE
    return (ushort_t)r;
}

__device__ __forceinline__ float fast_sqrt(float x) {
    return __builtin_amdgcn_sqrtf(x);     // v_sqrt_f32
}
__device__ __forceinline__ float fast_exp2(float x) {
    return __builtin_amdgcn_exp2f(x);     // v_exp_f32
}

__device__ __forceinline__ void decode_slot(int slot, int& z, int& bi, int& bj) {
    if (slot >= 272) {
        z = 2; int t = slot - 272; bi = t >> 4; bj = t & 15;
    } else {
        z = (slot >= 136) ? 1 : 0;
        int t = slot - z * 136;
        // triangular n=16: row b starts at cum(b) = b*(33-b)/2
        int b = (int)(16.5f - sqrtf(272.25f - 2.0f * (float)t));
        while (b * (33 - b) / 2 > t) --b;
        while ((b + 1) * (32 - b) / 2 <= t) ++b;
        bi = b;
        bj = bi + (t - bi * (33 - bi) / 2);
    }
}

// Kernel 0: fp32 row norms + bf16 (RTNE) copies of xs, xt.
__global__ __launch_bounds__(256) void norm_cvt(
        const float* __restrict__ xs, const float* __restrict__ xt,
        ushort_t* __restrict__ xsb, ushort_t* __restrict__ xtb,
        float* __restrict__ norms) {
    int w = threadIdx.x >> 6;
    int lane = threadIdx.x & 63;
    int row = blockIdx.x * 4 + w;              // 0..8191
    const float* src = (row < BN) ? xs + (size_t)row * KD
                                  : xt + (size_t)(row - BN) * KD;
    ushort_t* dst = (row < BN) ? xsb + (size_t)row * KD
                               : xtb + (size_t)(row - BN) * KD;
    float4 v = ((const float4*)src)[lane];
    float s = v.x * v.x + v.y * v.y + v.z * v.z + v.w * v.w;
#pragma unroll
    for (int off = 32; off > 0; off >>= 1) s += __shfl_xor(s, off, 64);
    if (lane == 0) norms[row] = s;
    ushort4 o;
    o.x = f2bf(v.x); o.y = f2bf(v.y); o.z = f2bf(v.z); o.w = f2bf(v.w);
    ((ushort4*)dst)[lane] = o;
}

// -------- distance GEMM (256^2 tile, 8 waves, dbuf'd LDS, counted vmcnt), run twice --------
// PASS 1: per-tile sum of d -> p1[slot] (plain store, c1-weighted)
// PASS 2: self-reduce p1 -> per-z mean, recompute d, exp-sum -> p2[slot]
// launch_bounds(512, 1): 8-wave block + 128 KiB LDS => 1 block/CU; min-waves=1
// gives the 256-VGPR budget (acc[8][4] alone is 128 VGPR — (512,2) spilled 32 MB).

template <int PASS>
__global__ __launch_bounds__(512, 1) void mmd_gemm(
        const ushort_t* __restrict__ xsb, const ushort_t* __restrict__ xtb,
        const float* __restrict__ norms,
        const float* __restrict__ p1, float* __restrict__ pout) {
    const int slot = blockIdx.x;
    int z, bi, bj;
    decode_slot(slot, z, bi, bj);

    const ushort_t* X = (z == 1) ? xtb : xsb;
    const ushort_t* Y = (z == 0) ? xsb : xtb;
    const float* nX = norms + ((z == 1) ? BN : 0);
    const float* nY = norms + ((z == 0) ? 0 : BN);

    const int tid = threadIdx.x;
    const int lane = tid & 63;
    const int w = tid >> 6;          // 0..7
    const int wr = w >> 2;           // 0..1 : 128-row band
    const int wc = w & 3;            // 0..3 : 64-col band
    const int m16 = lane & 15;
    const int q = lane >> 4;         // 0..3

    const int i0 = bi * TILE;
    const int j0 = bj * TILE;

    // LDS: double-buffered A,B tiles: 2 bufs x 2 (A,B) x 256x64 bf16 = 128 KiB
    __shared__ ushort_t sm[2][2][TILE * BK];
    __shared__ float red[8];
    __shared__ double rs[8][3];

    // PASS 2: self-reduce the 528 pass-1 tile partials (L2-hot ~2 KB) into per-z sums.
    float nhb = 0.0f;
    if (PASS == 2) {
        double a0 = 0.0, a1 = 0.0, a2 = 0.0;
        for (int s = tid; s < NSLOT; s += 512) {
            double v = (double)p1[s];
            if (s < 136) a0 += v; else if (s < 272) a1 += v; else a2 += v;
        }
#pragma unroll
        for (int off = 32; off > 0; off >>= 1) {
            a0 += __shfl_xor(a0, off, 64);
            a1 += __shfl_xor(a1, off, 64);
            a2 += __shfl_xor(a2, off, 64);
        }
        if (lane == 0) { rs[w][0] = a0; rs[w][1] = a1; rs[w][2] = a2; }
        __syncthreads();
        double sz = 0.0;
#pragma unroll
        for (int ww = 0; ww < 8; ++ww) sz += rs[ww][z];
        double mz = sz * (1.0 / 16777216.0);              // mean over 4096^2
        nhb = (float)(-1.4426950408889634 / (4.0 * mz));  // alpha=2 exponent scale
    }

    // staging geometry: per k-step, A tile = 2048 x 16B chunks, B same.
    // thread -> (row, chunk): chunk_id = t*512 + tid; r = t*64 + (tid>>3); c = tid&7.
    // XOR-swizzled source column, linear LDS dest (global_load_lds constraint).
    const int rbase = tid >> 3;
    const int gc = (tid & 7) ^ (rbase & 7);     // t-invariant: (t*64)%8 == 0
    const size_t baseA = (size_t)(i0 + rbase) * KD + gc * 8;
    const size_t baseB = (size_t)(j0 + rbase) * KD + gc * 8;

    f32x4 acc[8][4] = {};

    auto stage = [&](int kt, int p) {
        const int kk = kt * BK;
        char* ldsA = (char*)&sm[p][0][0];
        char* ldsB = (char*)&sm[p][1][0];
#pragma unroll
        for (int t = 0; t < 4; ++t) {
            async_load16(X + baseA + (size_t)t * 64 * KD + kk, ldsA + t * 8192 + tid * 16);
            async_load16(Y + baseB + (size_t)t * 64 * KD + kk, ldsB + t * 8192 + tid * 16);
        }
    };

    auto compute = [&](int p) {
#pragma unroll
        for (int ks = 0; ks < 2; ++ks) {
            bf16x8 af[8], bfv[4];
            const int kap = ks * 4 + q;
            const int pos = kap ^ (m16 & 7);    // row&7 == m16&7 for all fragment rows
#pragma unroll
            for (int rg = 0; rg < 8; ++rg)
                af[rg] = *(const bf16x8*)&sm[p][0][(wr * 128 + rg * 16 + m16) * BK + pos * 8];
#pragma unroll
            for (int ng = 0; ng < 4; ++ng)
                bfv[ng] = *(const bf16x8*)&sm[p][1][(wc * 64 + ng * 16 + m16) * BK + pos * 8];
#pragma unroll
            for (int rg = 0; rg < 8; ++rg)
#pragma unroll
                for (int ng = 0; ng < 4; ++ng)
                    acc[rg][ng] = __builtin_amdgcn_mfma_f32_16x16x32_bf16(
                        af[rg], bfv[ng], acc[rg][ng], 0, 0, 0);
        }
    };

    // K-loop: 4 steps, double-buffered, counted vmcnt (never drain prefetch).
    stage(0, 0);
#pragma unroll
    for (int t = 0; t < 4; ++t) {
        const int p = t & 1;
        if (t < 3) {
            stage(t + 1, p ^ 1);
            asm volatile("s_waitcnt vmcnt(8)" ::: "memory");   // buf p's 8 loads done
        } else {
            asm volatile("s_waitcnt vmcnt(0)" ::: "memory");
        }
        __builtin_amdgcn_s_barrier();
        compute(p);
        if (t < 3) __builtin_amdgcn_s_barrier();   // readers of buf p done before t+1 restages it
    }

    // norms: loaded after the K-loop so they never perturb vmcnt counting.
    float nxv[32];
#pragma unroll
    for (int rg = 0; rg < 8; ++rg) {
        float4 nf = *(const float4*)&nX[i0 + wr * 128 + rg * 16 + q * 4];
        nxv[rg * 4 + 0] = nf.x; nxv[rg * 4 + 1] = nf.y;
        nxv[rg * 4 + 2] = nf.z; nxv[rg * 4 + 3] = nf.w;
    }
    float nyv[4];
#pragma unroll
    for (int ng = 0; ng < 4; ++ng)
        nyv[ng] = nY[j0 + wc * 64 + ng * 16 + m16];

    const bool diag = (z < 2 && bi == bj);
    float local = 0.0f;
#pragma unroll
    for (int rg = 0; rg < 8; ++rg) {
#pragma unroll
        for (int ng = 0; ng < 4; ++ng) {
#pragma unroll
            for (int rr = 0; rr < 4; ++rr) {
                int i = wr * 128 + rg * 16 + q * 4 + rr;   // tile-local
                int j = wc * 64 + ng * 16 + m16;
                float sq = nxv[rg * 4 + rr] + nyv[ng] - 2.0f * acc[rg][ng][rr];
                sq = fmaxf(sq, 0.0f);
                float d = fast_sqrt(sq);
                if (diag && i == j) d = 0.0f;              // exact-zero diagonal
                if (PASS == 1) {
                    local += d;
                } else {
                    // sum over alphas {1/8,1/4,1/2,1,2}: u+u^2+u^4+u^8+u^16, u=2^(d*nhb)
                    float u = fast_exp2(d * nhb);
                    float u2 = u * u;
                    float u4 = u2 * u2;
                    float u8 = u4 * u4;
                    float u16 = u8 * u8;
                    local += (u + u2) + (u4 + u8) + u16;
                }
            }
        }
    }

#pragma unroll
    for (int off = 32; off > 0; off >>= 1) local += __shfl_xor(local, off, 64);
    if (lane == 0) red[w] = local;
    __syncthreads();
    if (tid == 0) {
        float bs = 0.0f;
#pragma unroll
        for (int ww = 0; ww < 8; ++ww) bs += red[ww];
        float coef;
        if (PASS == 1) coef = (z < 2 && bi != bj) ? 2.0f : 1.0f;   // mean weight
        else           coef = (z == 2) ? -2.0f : ((bi != bj) ? 2.0f : 1.0f);
        pout[slot] = coef * bs;                        // plain store, no atomic
    }
}

// -------- finalize: reduce pass-2 tile partials -> loss (1 block) --------

__global__ __launch_bounds__(256) void mmd_finalize2(
        const float* __restrict__ p2, float* __restrict__ out) {
    const int tid = threadIdx.x;
    double acc = 0.0;
    for (int s = tid; s < NSLOT; s += 256) acc += (double)p2[s];
    const int lane = tid & 63, w = tid >> 6;
#pragma unroll
    for (int off = 32; off > 0; off >>= 1) acc += __shfl_xor(acc, off, 64);
    __shared__ double r[4];
    if (lane == 0) r[w] = acc;
    __syncthreads();
    if (tid == 0) {
        double S = r[0] + r[1] + r[2] + r[3];
        double l = sqrt(S / ((double)BN * (double)(BN - 1)));
        float f = (float)l;
        if (!(f == f)) f = 0.0f;
        out[0] = f;
    }
}

extern "C" void kernel_launch(void* const* d_in, const int* in_sizes, int n_in,
                              void* d_out, int out_size, void* d_ws, size_t ws_size,
                              hipStream_t stream) {
    const float* xs = (const float*)d_in[0];
    const float* xt = (const float*)d_in[1];
    float* out = (float*)d_out;

    char* ws = (char*)d_ws;
    float* norms = (float*)ws;                     // 8192 floats -> 32768
    float* p1 = (float*)(ws + 32768);              // 528 floats -> pad to 35072
    float* p2 = (float*)(ws + 35072);              // 528 floats -> pad to 37376
    ushort_t* xsb = (ushort_t*)(ws + 37376);       // 2 MB
    ushort_t* xtb = xsb + (size_t)BN * KD;         // 2 MB -> ends 4231680

    size_t need = 4231680;
    if (ws_size < need) {
        (void)hipMemsetAsync(d_out, 0xC0, 4, stream);    // diagnostic marker
        return;
    }

    norm_cvt<<<2048, 256, 0, stream>>>(xs, xt, xsb, xtb, norms);
    mmd_gemm<1><<<NSLOT, 512, 0, stream>>>(xsb, xtb, norms, p1, p1);
    mmd_gemm<2><<<NSLOT, 512, 0, stream>>>(xsb, xtb, norms, p1, p2);
    mmd_finalize2<<<1, 256, 0, stream>>>(p2, out);
}

// Round 5
// 140.827 us; speedup vs baseline: 1.0625x; 1.0560x over previous
//
#include <hip/hip_runtime.h>

#define BN 4096
#define KD 256
#define TILE 256
#define BK 64

typedef short bf16x8 __attribute__((ext_vector_type(8)));
typedef float f32x4 __attribute__((ext_vector_type(4)));
typedef unsigned short ushort_t;
typedef unsigned int uint_t;

// 256x256 tile slots: z=0 upper-tri 136, z=1 upper-tri 136, z=2 full 256 -> 528
#define NSLOT 528

__device__ inline void async_load16(const void* g, void* l) {
    __builtin_amdgcn_global_load_lds((const __attribute__((address_space(1))) void*)g,
                                     (__attribute__((address_space(3))) void*)l,
                                     16, 0, 0);
}

__device__ inline ushort_t f2bf(float f) {
    union { float f; unsigned int u; } x;
    x.f = f;
    unsigned int u = x.u;
    unsigned int r = (u + 0x7fffu + ((u >> 16) & 1u)) >> 16;  // RTNE
    return (ushort_t)r;
}

__device__ __forceinline__ float fast_sqrt(float x) {
    return __builtin_amdgcn_sqrtf(x);     // v_sqrt_f32
}
__device__ __forceinline__ float fast_exp2(float x) {
    return __builtin_amdgcn_exp2f(x);     // v_exp_f32
}

__device__ __forceinline__ void decode_slot(int slot, int& z, int& bi, int& bj) {
    if (slot >= 272) {
        z = 2; int t = slot - 272; bi = t >> 4; bj = t & 15;
    } else {
        z = (slot >= 136) ? 1 : 0;
        int t = slot - z * 136;
        // triangular n=16: row b starts at cum(b) = b*(33-b)/2
        int b = (int)(16.5f - sqrtf(272.25f - 2.0f * (float)t));
        while (b * (33 - b) / 2 > t) --b;
        while ((b + 1) * (32 - b) / 2 <= t) ++b;
        bi = b;
        bj = bi + (t - bi * (33 - bi) / 2);
    }
}

// Kernel 0: fp32 row norms + bf16 (RTNE) copies of xs, xt.
__global__ __launch_bounds__(256) void norm_cvt(
        const float* __restrict__ xs, const float* __restrict__ xt,
        ushort_t* __restrict__ xsb, ushort_t* __restrict__ xtb,
        float* __restrict__ norms) {
    int w = threadIdx.x >> 6;
    int lane = threadIdx.x & 63;
    int row = blockIdx.x * 4 + w;              // 0..8191
    const float* src = (row < BN) ? xs + (size_t)row * KD
                                  : xt + (size_t)(row - BN) * KD;
    ushort_t* dst = (row < BN) ? xsb + (size_t)row * KD
                               : xtb + (size_t)(row - BN) * KD;
    float4 v = ((const float4*)src)[lane];
    float s = v.x * v.x + v.y * v.y + v.z * v.z + v.w * v.w;
#pragma unroll
    for (int off = 32; off > 0; off >>= 1) s += __shfl_xor(s, off, 64);
    if (lane == 0) norms[row] = s;
    ushort4 o;
    o.x = f2bf(v.x); o.y = f2bf(v.y); o.z = f2bf(v.z); o.w = f2bf(v.w);
    ((ushort4*)dst)[lane] = o;
}

// -------- distance GEMM (256^2 tile, 8 waves, dbuf'd LDS, counted vmcnt), run twice --------
// PASS 1: per-tile sum of d -> p1[slot] (plain store, c1-weighted)
// PASS 2: self-reduce p1 -> per-z mean, recompute d, exp-sum -> p2[slot]
// Register budget: 8 waves/block = 2 waves/SIMD => HARD cap 256 regs/wave
// (arch VGPR + AGPR, unified file). acc[8][4] = 128 AGPR; everything else
// must stay under ~128 arch VGPRs -> A-fragments loaded one-at-a-time,
// 32-bit staging offsets, no epilogue norm array.

template <int PASS>
__global__ __launch_bounds__(512, 1) void mmd_gemm(
        const ushort_t* __restrict__ xsb, const ushort_t* __restrict__ xtb,
        const float* __restrict__ norms,
        const float* __restrict__ p1, float* __restrict__ pout) {
    const int slot = blockIdx.x;
    int z, bi, bj;
    decode_slot(slot, z, bi, bj);

    const ushort_t* X = (z == 1) ? xtb : xsb;
    const ushort_t* Y = (z == 0) ? xsb : xtb;
    const float* nX = norms + ((z == 1) ? BN : 0);
    const float* nY = norms + ((z == 0) ? 0 : BN);

    const int tid = threadIdx.x;
    const int lane = tid & 63;
    const int w = tid >> 6;          // 0..7
    const int wr = w >> 2;           // 0..1 : 128-row band
    const int wc = w & 3;            // 0..3 : 64-col band
    const int m16 = lane & 15;
    const int q = lane >> 4;         // 0..3

    const int i0 = bi * TILE;
    const int j0 = bj * TILE;

    // LDS: double-buffered A,B tiles: 2 bufs x 2 (A,B) x 256x64 bf16 = 128 KiB
    __shared__ ushort_t sm[2][2][TILE * BK];
    __shared__ float red[8];
    __shared__ double rs[8][3];

    // PASS 2: self-reduce the 528 pass-1 tile partials (L2-hot ~2 KB) into per-z sums.
    float nhb = 0.0f;
    if (PASS == 2) {
        double a0 = 0.0, a1 = 0.0, a2 = 0.0;
        for (int s = tid; s < NSLOT; s += 512) {
            double v = (double)p1[s];
            if (s < 136) a0 += v; else if (s < 272) a1 += v; else a2 += v;
        }
#pragma unroll
        for (int off = 32; off > 0; off >>= 1) {
            a0 += __shfl_xor(a0, off, 64);
            a1 += __shfl_xor(a1, off, 64);
            a2 += __shfl_xor(a2, off, 64);
        }
        if (lane == 0) { rs[w][0] = a0; rs[w][1] = a1; rs[w][2] = a2; }
        __syncthreads();
        double sz = 0.0;
#pragma unroll
        for (int ww = 0; ww < 8; ++ww) sz += rs[ww][z];
        double mz = sz * (1.0 / 16777216.0);              // mean over 4096^2
        nhb = (float)(-1.4426950408889634 / (4.0 * mz));  // alpha=2 exponent scale
    }

    // staging geometry: per k-step, A tile = 2048 x 16B chunks, B same.
    // thread -> (row, chunk): r = t*64 + (tid>>3); c = tid&7 (XOR-swizzled source col,
    // linear LDS dest). 32-bit BYTE offsets: buffers are ~2 MB, so uint suffices.
    const int rbase = tid >> 3;
    const int gc = (tid & 7) ^ (rbase & 7);     // t-invariant: (t*64)%8 == 0
    const uint_t offA = ((uint_t)(i0 + rbase) * KD + (uint_t)gc * 8) * 2u;
    const uint_t offB = ((uint_t)(j0 + rbase) * KD + (uint_t)gc * 8) * 2u;
    const char* Xc = (const char*)X;
    const char* Yc = (const char*)Y;

    f32x4 acc[8][4] = {};

    auto stage = [&](int kt, int p) {
        const uint_t kb = (uint_t)(kt * BK * 2);
        char* ldsA = (char*)&sm[p][0][0] + tid * 16;
        char* ldsB = (char*)&sm[p][1][0] + tid * 16;
#pragma unroll
        for (int t = 0; t < 4; ++t) {
            const uint_t rowoff = (uint_t)(t * 64 * KD * 2);
            async_load16(Xc + (offA + rowoff + kb), ldsA + t * 8192);
            async_load16(Yc + (offB + rowoff + kb), ldsB + t * 8192);
        }
    };

    auto compute = [&](int p) {
#pragma unroll
        for (int ks = 0; ks < 2; ++ks) {
            const int kap = ks * 4 + q;
            const int pos = kap ^ (m16 & 7);    // row&7 == m16&7 for all fragment rows
            bf16x8 bfv[4];
#pragma unroll
            for (int ng = 0; ng < 4; ++ng)
                bfv[ng] = *(const bf16x8*)&sm[p][1][(wc * 64 + ng * 16 + m16) * BK + pos * 8];
#pragma unroll
            for (int rg = 0; rg < 8; ++rg) {
                bf16x8 a = *(const bf16x8*)&sm[p][0][(wr * 128 + rg * 16 + m16) * BK + pos * 8];
#pragma unroll
                for (int ng = 0; ng < 4; ++ng)
                    acc[rg][ng] = __builtin_amdgcn_mfma_f32_16x16x32_bf16(
                        a, bfv[ng], acc[rg][ng], 0, 0, 0);
            }
        }
    };

    // K-loop: 4 steps, double-buffered, counted vmcnt (never drain prefetch).
    stage(0, 0);
#pragma unroll
    for (int t = 0; t < 4; ++t) {
        const int p = t & 1;
        if (t < 3) {
            stage(t + 1, p ^ 1);
            asm volatile("s_waitcnt vmcnt(8)" ::: "memory");   // buf p's 8 loads done
        } else {
            asm volatile("s_waitcnt vmcnt(0)" ::: "memory");
        }
        __builtin_amdgcn_s_barrier();
        compute(p);
        if (t < 3) __builtin_amdgcn_s_barrier();   // readers of buf p done before t+1 restages it
    }

    float nyv[4];
#pragma unroll
    for (int ng = 0; ng < 4; ++ng)
        nyv[ng] = nY[j0 + wc * 64 + ng * 16 + m16];

    const bool diag = (z < 2 && bi == bj);
    float local = 0.0f;
#pragma unroll
    for (int rg = 0; rg < 8; ++rg) {
        float4 nf = *(const float4*)&nX[i0 + wr * 128 + rg * 16 + q * 4];
        float nx4[4] = {nf.x, nf.y, nf.z, nf.w};
#pragma unroll
        for (int ng = 0; ng < 4; ++ng) {
#pragma unroll
            for (int rr = 0; rr < 4; ++rr) {
                int i = wr * 128 + rg * 16 + q * 4 + rr;   // tile-local
                int j = wc * 64 + ng * 16 + m16;
                float sq = nx4[rr] + nyv[ng] - 2.0f * acc[rg][ng][rr];
                sq = fmaxf(sq, 0.0f);
                float d = fast_sqrt(sq);
                if (diag && i == j) d = 0.0f;              // exact-zero diagonal
                if (PASS == 1) {
                    local += d;
                } else {
                    // sum over alphas {1/8,1/4,1/2,1,2}: u+u^2+u^4+u^8+u^16, u=2^(d*nhb)
                    float u = fast_exp2(d * nhb);
                    float u2 = u * u;
                    float u4 = u2 * u2;
                    float u8 = u4 * u4;
                    float u16 = u8 * u8;
                    local += (u + u2) + (u4 + u8) + u16;
                }
            }
        }
    }

#pragma unroll
    for (int off = 32; off > 0; off >>= 1) local += __shfl_xor(local, off, 64);
    if (lane == 0) red[w] = local;
    __syncthreads();
    if (tid == 0) {
        float bs = 0.0f;
#pragma unroll
        for (int ww = 0; ww < 8; ++ww) bs += red[ww];
        float coef;
        if (PASS == 1) coef = (z < 2 && bi != bj) ? 2.0f : 1.0f;   // mean weight
        else           coef = (z == 2) ? -2.0f : ((bi != bj) ? 2.0f : 1.0f);
        pout[slot] = coef * bs;                        // plain store, no atomic
    }
}

// -------- finalize: reduce pass-2 tile partials -> loss (1 block) --------

__global__ __launch_bounds__(256) void mmd_finalize2(
        const float* __restrict__ p2, float* __restrict__ out) {
    const int tid = threadIdx.x;
    double acc = 0.0;
    for (int s = tid; s < NSLOT; s += 256) acc += (double)p2[s];
    const int lane = tid & 63, w = tid >> 6;
#pragma unroll
    for (int off = 32; off > 0; off >>= 1) acc += __shfl_xor(acc, off, 64);
    __shared__ double r[4];
    if (lane == 0) r[w] = acc;
    __syncthreads();
    if (tid == 0) {
        double S = r[0] + r[1] + r[2] + r[3];
        double l = sqrt(S / ((double)BN * (double)(BN - 1)));
        float f = (float)l;
        if (!(f == f)) f = 0.0f;
        out[0] = f;
    }
}

extern "C" void kernel_launch(void* const* d_in, const int* in_sizes, int n_in,
                              void* d_out, int out_size, void* d_ws, size_t ws_size,
                              hipStream_t stream) {
    const float* xs = (const float*)d_in[0];
    const float* xt = (const float*)d_in[1];
    float* out = (float*)d_out;

    char* ws = (char*)d_ws;
    float* norms = (float*)ws;                     // 8192 floats -> 32768
    float* p1 = (float*)(ws + 32768);              // 528 floats -> pad to 35072
    float* p2 = (float*)(ws + 35072);              // 528 floats -> pad to 37376
    ushort_t* xsb = (ushort_t*)(ws + 37376);       // 2 MB
    ushort_t* xtb = xsb + (size_t)BN * KD;         // 2 MB -> ends 4231680

    size_t need = 4231680;
    if (ws_size < need) {
        (void)hipMemsetAsync(d_out, 0xC0, 4, stream);    // diagnostic marker
        return;
    }

    norm_cvt<<<2048, 256, 0, stream>>>(xs, xt, xsb, xtb, norms);
    mmd_gemm<1><<<NSLOT, 512, 0, stream>>>(xsb, xtb, norms, p1, p1);
    mmd_gemm<2><<<NSLOT, 512, 0, stream>>>(xsb, xtb, norms, p1, p2);
    mmd_finalize2<<<1, 256, 0, stream>>>(p2, out);
}